// Round 11
// baseline (161.777 us; speedup 1.0000x reference)
//
#include <hip/hip_runtime.h>

typedef float f4 __attribute__((ext_vector_type(4)));
typedef float f2 __attribute__((ext_vector_type(2)));
typedef short s8 __attribute__((ext_vector_type(8)));

union FU { unsigned u[4]; s8 s; };

// packed f32x2 -> bf16x2 (RNE) in one instruction
__device__ __forceinline__ unsigned cvtpk(float lo, float hi){
  unsigned r;
  asm("v_cvt_pk_bf16_f32 %0, %1, %2" : "=v"(r) : "v"(lo), "v"(hi));
  return r;
}

// ---- bf16 helpers ----
__device__ __forceinline__ float bflo(unsigned v){ return __uint_as_float(v << 16); }
__device__ __forceinline__ float bfhi(unsigned v){ return __uint_as_float(v & 0xFFFF0000u); }

// ---- index loader: handles int32 or int64 edge/batch arrays ----
__device__ __forceinline__ int ld_idx(const void* p, int i, int is64){
  if (is64) return (int)((const long long*)p)[i];
  return ((const int*)p)[i];
}

// wave-level dtype detect (1 => int64): int64 => every odd 32-bit word zero.
__device__ __forceinline__ int detect64(const unsigned* __restrict__ e_raw, int e){
  int lane = threadIdx.x & 63;
  int lim = (e < 1024) ? e : 1024;
  int nz = 0;
  for (int i = lane; i < lim; i += 64) nz |= (e_raw[2*i + 1] != 0u);
  return (__ballot(nz != 0) == 0ull) ? 1 : 0;
}

// ---- MFMA GEMM body: Yb[n,NC](bf16) = X[n,128] @ W[128,NC](f32)
// BIN=0: X is f32 (converted during staging); BIN=1: X already bf16.
template<int NC, int BIN>
__device__ __forceinline__ void gemm_body(const void* __restrict__ Xv,
                                          const float* __restrict__ W,
                                          unsigned short* __restrict__ Yb,
                                          int n, int blk, char* Alds){
  constexpr int NCF = NC/16;
  constexpr int WPC = 8/NCF;
  constexpr int RT  = 8/WPC;
  const int tid  = threadIdx.x;
  const int wave = tid >> 6, lane = tid & 63;
  const int rb = blk * 128;

  const int cbase = (wave % NCF) * 16;
  const int rt0   = (wave / NCF) * RT;
  const int col   = cbase + (lane & 15);
  const int kr0   = (lane >> 4) * 8;
  FU bu[4];
#pragma unroll
  for (int ks = 0; ks < 4; ++ks){
    float wv[8];
#pragma unroll
    for (int j = 0; j < 8; ++j) wv[j] = W[(size_t)(ks*32 + kr0 + j)*NC + col];
#pragma unroll
    for (int q = 0; q < 4; ++q) bu[ks].u[q] = cvtpk(wv[2*q], wv[2*q+1]);
  }

  // stage A tile (128 rows x 128 k) as bf16, byte ^= (row&7)<<4
  for (int i = tid; i < 128*32; i += 512){
    int row = i >> 5, kq = i & 31;            // kq: 8-byte unit along k
    int rsrc = rb + row; if (rsrc >= n) rsrc = n - 1;
    uint2 dw;
    if (BIN){
      dw = ((const uint2*)Xv)[(size_t)rsrc*32 + kq];      // 4 bf16 copy
    } else {
      f4 xv = ((const f4*)Xv)[(size_t)rsrc*32 + kq];
      dw = make_uint2(cvtpk(xv[0], xv[1]), cvtpk(xv[2], xv[3]));
    }
    int byte = (row*256 + kq*8) ^ ((row & 7) << 4);
    *reinterpret_cast<uint2*>(Alds + byte) = dw;
  }
  __syncthreads();

  f4 acc[RT];
#pragma unroll
  for (int rt = 0; rt < RT; ++rt) acc[rt] = 0.0f;

#pragma unroll
  for (int rt = 0; rt < RT; ++rt){
    const int arow = (rt0 + rt)*16 + (lane & 15);
#pragma unroll
    for (int ks = 0; ks < 4; ++ks){
      int kb = ks*32 + kr0;
      int byte = (arow*256 + kb*2) ^ ((arow & 7) << 4);
      s8 a = *reinterpret_cast<const s8*>(Alds + byte);
      acc[rt] = __builtin_amdgcn_mfma_f32_16x16x32_bf16(a, bu[ks].s, acc[rt], 0, 0, 0);
    }
  }

#pragma unroll
  for (int rt = 0; rt < RT; ++rt){
    int rowb = rb + (rt0 + rt)*16 + 4*(lane >> 4);
#pragma unroll
    for (int r = 0; r < 4; ++r){
      int row = rowb + r;
      if (row < n) Yb[(size_t)row*NC + col] = (unsigned short)cvtpk(acc[rt][r], acc[rt][r]);
    }
  }
}

template<int NC, int BIN>
__global__ __launch_bounds__(512) void gemm_k(const void* __restrict__ X,
                                              const float* __restrict__ W,
                                              unsigned short* __restrict__ Yb, int n){
  __shared__ int4 AldsV[2048];
  gemm_body<NC, BIN>(X, W, Yb, n, blockIdx.x, (char*)AldsV);
}

// ---- fused: gemm1 (blocks < GB) || bucket-count + edge compaction.
// etmp[i] = s | (d&127)<<16 | (d>>7)<<23  (needs s<65536, NBK<512)
// counts layout: counts[bin*CB + blk] (bin-major flat order)
__global__ __launch_bounds__(512) void fused1_k(const float* __restrict__ X,
                                                const float* __restrict__ W1,
                                                unsigned short* __restrict__ Yb,
                                                const void* __restrict__ eidx,
                                                const void* __restrict__ batchp,
                                                int* __restrict__ counts,
                                                unsigned* __restrict__ etmp,
                                                int* __restrict__ batch32,
                                                int n, int e, int GB, int CB){
  __shared__ int4 AldsV[2048];
  __shared__ int hist[512];
  int blk = blockIdx.x;
  if (blk < GB){
    gemm_body<128, 0>(X, W1, Yb, n, blk, (char*)AldsV);
    return;
  }
  blk -= GB;                          // 0..CB-1
  const int NBK = (n + 127) >> 7;
  for (int i = threadIdx.x; i < NBK; i += 512) hist[i] = 0;
  __syncthreads();
  int is64 = detect64((const unsigned*)eidx, e);
  int CHK = (e + CB - 1) / CB;
  int beg = blk*CHK, end = min(e, beg + CHK);
  for (int i = beg + (int)threadIdx.x; i < end; i += 512){
    int s = ld_idx(eidx, i, is64);
    int d = ld_idx(eidx, e + i, is64);
    atomicAdd(&hist[d >> 7], 1);      // LDS atomic
    etmp[i] = (unsigned)s | ((unsigned)(d & 127) << 16) | ((unsigned)(d >> 7) << 23);
  }
  __syncthreads();
  for (int i = threadIdx.x; i < NBK; i += 512) counts[i*CB + blk] = hist[i];
  for (int i = blk*512 + (int)threadIdx.x; i < n; i += CB*512)
    batch32[i] = ld_idx(batchp, i, is64);
}

// ---- flat scan level 1: block-local exclusive scan + block sums.
// CB == 256 == scan width so scan-block b == bucket b; block 0 zeroes outsum.
__global__ void scanA_k(const int* __restrict__ counts, int* __restrict__ base,
                        int* __restrict__ bsum, int L,
                        float* __restrict__ outsum, int totalOut){
  __shared__ int sh[256];
  int tid = threadIdx.x;
  int i = blockIdx.x*256 + tid;
  int v = (i < L) ? counts[i] : 0;
  sh[tid] = v; __syncthreads();
  for (int off = 1; off < 256; off <<= 1){
    int t = (tid >= off) ? sh[tid - off] : 0;
    __syncthreads();
    sh[tid] += t;
    __syncthreads();
  }
  if (i < L) base[i] = sh[tid] - v;
  if (tid == 255) bsum[blockIdx.x] = sh[255];
  if (blockIdx.x == 0){
    for (int k = tid; k < totalOut; k += 256) outsum[k] = 0.0f;
  }
}

// ---- scatter (with inline level-2 scan of bsum): edges -> bucket groups.
// Each block redundantly scans bsum[NBK] in LDS; block 0 publishes bsumS.
__global__ __launch_bounds__(512) void scat_k(const unsigned* __restrict__ etmp,
                                              const int* __restrict__ base,
                                              const int* __restrict__ bsum,
                                              int* __restrict__ bsumS,
                                              int* __restrict__ packed,
                                              int n, int e, int CB){
  __shared__ int sh[512];
  __shared__ int cur[512];
  int blk = blockIdx.x, tid = threadIdx.x;
  const int NBK = (n + 127) >> 7;
  int v = (tid < NBK) ? bsum[tid] : 0;
  sh[tid] = v; __syncthreads();
  for (int o = 1; o < 512; o <<= 1){
    int t = (tid >= o) ? sh[tid - o] : 0;
    __syncthreads();
    sh[tid] += t;
    __syncthreads();
  }
  int ex = sh[tid] - v;                     // exclusive bucket base
  if (tid < NBK) cur[tid] = ex + base[tid*CB + blk];
  if (blk == 0){
    if (tid < NBK) bsumS[tid] = ex;
    if (tid == NBK - 1) bsumS[NBK] = sh[tid];   // total = e
  }
  __syncthreads();
  int CHK = (e + CB - 1) / CB;
  int beg = blk*CHK, end = min(e, beg + CHK);
  for (int i = beg + tid; i < end; i += 512){
    unsigned w = etmp[i];
    int pos = atomicAdd(&cur[w >> 23], 1);
    packed[pos] = (int)(w & 0x7FFFFFu);     // s | dlow<<16
  }
}

// ---- per-bucket CSR build: 128-bin LDS counting sort, degrees, dinv ----
#define CSR_CAP 6144
__global__ __launch_bounds__(256) void csr_k(const int* __restrict__ packed,
                                             const int* __restrict__ bsumS,
                                             int* __restrict__ esrcS,
                                             int* __restrict__ rowptr,
                                             float* __restrict__ dinv, int n, int e){
  __shared__ int vals[CSR_CAP];
  __shared__ int hist[128], off[128], cur[128];
  int b = blockIdx.x, tid = threadIdx.x;
  if (b == 0 && tid == 0) rowptr[n] = e;
  int sbeg = bsumS[b], send = bsumS[b + 1];
  int m = send - sbeg;
  int mL = min(m, CSR_CAP);
  for (int i = tid; i < mL; i += 256) vals[i] = packed[sbeg + i];
  if (tid < 128) hist[tid] = 0;
  __syncthreads();
  for (int i = tid; i < m; i += 256){
    int v = (i < CSR_CAP) ? vals[i] : packed[sbeg + i];
    atomicAdd(&hist[(v >> 16) & 127], 1);
  }
  __syncthreads();
  if (tid < 128) off[tid] = hist[tid];
  __syncthreads();
  for (int o = 1; o < 128; o <<= 1){
    int v = 0;
    if (tid < 128 && tid >= o) v = off[tid - o];
    __syncthreads();
    if (tid < 128) off[tid] += v;
    __syncthreads();
  }
  if (tid < 128){
    int ex = off[tid] - hist[tid];      // exclusive
    cur[tid] = ex;
    int node = b*128 + tid;
    if (node < n){
      rowptr[node] = sbeg + ex;
      dinv[node] = rsqrtf((float)hist[tid] + 1.0f);
    }
  }
  __syncthreads();
  for (int i = tid; i < m; i += 256){
    int v = (i < CSR_CAP) ? vals[i] : packed[sbeg + i];
    int pos = atomicAdd(&cur[(v >> 16) & 127], 1);
    esrcS[sbeg + pos] = v & 0xFFFF;
  }
}

// ---- layer-1 aggregation + bias + relu -> bf16 h1. One wave per node,
// unroll-by-16 load-then-FMA (16 gathers in flight per wave).
__global__ __launch_bounds__(256) void agg128_k(const unsigned short* __restrict__ HWb,
                                                const float* __restrict__ dinv,
                                                const int* __restrict__ rowptr,
                                                const int* __restrict__ esrcS,
                                                const float* __restrict__ bias,
                                                unsigned* __restrict__ Hb, int n){
  int wid  = (blockIdx.x*256 + threadIdx.x) >> 6;
  int lane = threadIdx.x & 63;
  if (wid >= n) return;
  wid = __builtin_amdgcn_readfirstlane(wid);
  float di = dinv[wid];
  float di2 = di * di;
  int beg = __builtin_amdgcn_readfirstlane(rowptr[wid]);
  int end = __builtin_amdgcn_readfirstlane(rowptr[wid + 1]);
  unsigned sv = ((const unsigned*)(HWb + (size_t)wid*128))[lane];
  float a0 = bflo(sv) * di2, a1 = bfhi(sv) * di2;
  int j = beg;
  for (; j + 16 <= end; j += 16){
    int s[16]; float dv[16]; unsigned v[16];
#pragma unroll
    for (int t = 0; t < 16; ++t) s[t] = esrcS[j + t];
#pragma unroll
    for (int t = 0; t < 16; ++t){
      dv[t] = dinv[s[t]];
      v[t] = ((const unsigned*)(HWb + (size_t)s[t]*128))[lane];
    }
#pragma unroll
    for (int t = 0; t < 16; ++t){
      float wt = dv[t] * di;
      a0 += bflo(v[t]) * wt;
      a1 += bfhi(v[t]) * wt;
    }
  }
  for (; j + 4 <= end; j += 4){
    int s[4]; float dv[4]; unsigned v[4];
#pragma unroll
    for (int t = 0; t < 4; ++t) s[t] = esrcS[j + t];
#pragma unroll
    for (int t = 0; t < 4; ++t){
      dv[t] = dinv[s[t]];
      v[t] = ((const unsigned*)(HWb + (size_t)s[t]*128))[lane];
    }
#pragma unroll
    for (int t = 0; t < 4; ++t){
      float wt = dv[t] * di;
      a0 += bflo(v[t]) * wt;
      a1 += bfhi(v[t]) * wt;
    }
  }
  for (; j < end; ++j){
    int s = esrcS[j];
    float wt = dinv[s] * di;
    unsigned v = ((const unsigned*)(HWb + (size_t)s*128))[lane];
    a0 += bflo(v) * wt;
    a1 += bfhi(v) * wt;
  }
  f2 bb = ((const f2*)bias)[lane];
  a0 = fmaxf(a0 + bb[0], 0.0f);
  a1 = fmaxf(a1 + bb[1], 0.0f);
  Hb[(size_t)wid*64 + lane] = cvtpk(a0, a1);
}

// ---- layer-2 aggregation + bias + relu + FUSED mean-pool accumulate:
// each wave computes h2[node] (64 cols) and atomically adds it into
// outsum[batch[node]] — no h2 materialization, no pool kernel.
__global__ __launch_bounds__(256) void agg64p_k(const unsigned short* __restrict__ HWb,
                                                const float* __restrict__ dinv,
                                                const int* __restrict__ rowptr,
                                                const int* __restrict__ esrcS,
                                                const float* __restrict__ bias,
                                                const int* __restrict__ batch32,
                                                float* __restrict__ outsum, int n){
  int wid  = (blockIdx.x*256 + threadIdx.x) >> 6;
  int lane = threadIdx.x & 63;
  if (wid >= n) return;
  wid = __builtin_amdgcn_readfirstlane(wid);
  float di = dinv[wid];
  float di2 = di * di;
  int beg = __builtin_amdgcn_readfirstlane(rowptr[wid]);
  int end = __builtin_amdgcn_readfirstlane(rowptr[wid + 1]);
  float acc = bflo((unsigned)HWb[(size_t)wid*64 + lane]) * di2;
  int j = beg;
  for (; j + 16 <= end; j += 16){
    int s[16]; float dv[16]; unsigned v[16];
#pragma unroll
    for (int t = 0; t < 16; ++t) s[t] = esrcS[j + t];
#pragma unroll
    for (int t = 0; t < 16; ++t){
      dv[t] = dinv[s[t]];
      v[t] = (unsigned)HWb[(size_t)s[t]*64 + lane];
    }
#pragma unroll
    for (int t = 0; t < 16; ++t) acc += bflo(v[t]) * (dv[t] * di);
  }
  for (; j + 4 <= end; j += 4){
    int s[4]; float dv[4]; unsigned v[4];
#pragma unroll
    for (int t = 0; t < 4; ++t) s[t] = esrcS[j + t];
#pragma unroll
    for (int t = 0; t < 4; ++t){
      dv[t] = dinv[s[t]];
      v[t] = (unsigned)HWb[(size_t)s[t]*64 + lane];
    }
#pragma unroll
    for (int t = 0; t < 4; ++t) acc += bflo(v[t]) * (dv[t] * di);
  }
  for (; j < end; ++j){
    int s = esrcS[j];
    acc += bflo((unsigned)HWb[(size_t)s*64 + lane]) * (dinv[s] * di);
  }
  acc = fmaxf(acc + bias[lane], 0.0f);
  int gid = batch32[wid];                    // wave-uniform
  unsafeAtomicAdd(&outsum[gid*64 + lane], acc);
}

// ---- finalize: graph sizes via binary search on sorted batch + divide ----
__global__ void fin_k(const float* __restrict__ outsum,
                      const int* __restrict__ batch32,
                      float* __restrict__ out, int n, int g){
  __shared__ int starts[257];
  int t = threadIdx.x;
  if (t <= g){
    int lo = 0, hi = n;
    while (lo < hi){ int mid = (lo + hi) >> 1; if (batch32[mid] < t) lo = mid + 1; else hi = mid; }
    starts[t] = lo;
  }
  __syncthreads();
  for (int idx = t; idx < (g << 6); idx += 256){
    int gi = idx >> 6;
    float c = (float)(starts[gi + 1] - starts[gi]);
    out[idx] = outsum[idx] / fmaxf(c, 1.0f);
  }
}

extern "C" void kernel_launch(void* const* d_in, const int* in_sizes, int n_in,
                              void* d_out, int out_size, void* d_ws, size_t ws_size,
                              hipStream_t stream){
  const float* x    = (const float*)d_in[0];
  const float* W1   = (const float*)d_in[1];
  const float* b1   = (const float*)d_in[2];
  const float* W2   = (const float*)d_in[3];
  const float* b2   = (const float*)d_in[4];
  const void*  eidx = d_in[5];
  const void*  batchp = d_in[6];
  const int n = in_sizes[0] / 128;    // 50000
  const int e = in_sizes[5] / 2;      // 800000
  const int g = out_size / 64;        // 64 graphs
  float* out = (float*)d_out;

  const int NBK = (n + 127) >> 7;     // dst buckets (n <= 65536 required)
  const int CB  = 256;                // count/scatter blocks (== scan width)
  const int GB  = (n + 127) / 128;    // gemm M-tiles
  const int L   = NBK * CB;           // flat counts length

  // ---- workspace layout ----
  char* w = (char*)d_ws;
  int* counts  = (int*)w;                     // L (bin-major)
  int* base    = counts + (size_t)L;          // L
  int* bsum    = base + (size_t)L;            // NBK
  int* bsumS   = bsum + NBK;                  // NBK+1 (scanned copy)
  int* rowptr  = bsumS + (NBK + 1);           // n+1
  int* batch32 = rowptr + (n + 1);            // n
  float* dinv  = (float*)(batch32 + n);       // n
  float* outsum = dinv + n;                   // out_size
  unsigned* etmp = (unsigned*)(outsum + out_size);   // e
  int* packed  = (int*)(etmp + e);            // e
  int* esrcS   = packed + e;                  // e
  size_t ofs = (size_t)((char*)(esrcS + e) - w);
  ofs = (ofs + 255) & ~(size_t)255;
  unsigned short* HWb = (unsigned short*)(w + ofs);   // n*128 bf16 (gemm out)
  size_t ofs2 = ofs + (size_t)n * 128 * 2;
  ofs2 = (ofs2 + 255) & ~(size_t)255;
  unsigned short* Hb = (unsigned short*)(w + ofs2);   // n*128 bf16 (h1)

  fused1_k<<<GB + CB, 512, 0, stream>>>(x, W1, HWb, eidx, batchp,
                                        counts, etmp, batch32, n, e, GB, CB);
  scanA_k<<<NBK, 256, 0, stream>>>(counts, base, bsum, L, outsum, out_size);
  scat_k<<<CB, 512, 0, stream>>>(etmp, base, bsum, bsumS, packed, n, e, CB);
  csr_k<<<NBK, 256, 0, stream>>>(packed, bsumS, esrcS, rowptr, dinv, n, e);

  agg128_k<<<(n + 3)/4, 256, 0, stream>>>(HWb, dinv, rowptr, esrcS, b1,
                                          (unsigned*)Hb, n);
  gemm_k<64, 1><<<GB, 512, 0, stream>>>(Hb, W2, HWb, n);
  agg64p_k<<<(n + 3)/4, 256, 0, stream>>>(HWb, dinv, rowptr, esrcS, b2,
                                          batch32, outsum, n);
  fin_k<<<1, 256, 0, stream>>>(outsum, batch32, out, n, g);
}

// Round 12
// 120.183 us; speedup vs baseline: 1.3461x; 1.3461x over previous
//
#include <hip/hip_runtime.h>

typedef float f4 __attribute__((ext_vector_type(4)));
typedef float f2 __attribute__((ext_vector_type(2)));
typedef short s8 __attribute__((ext_vector_type(8)));

union FU { unsigned u[4]; s8 s; };

// packed f32x2 -> bf16x2 (RNE) in one instruction
__device__ __forceinline__ unsigned cvtpk(float lo, float hi){
  unsigned r;
  asm("v_cvt_pk_bf16_f32 %0, %1, %2" : "=v"(r) : "v"(lo), "v"(hi));
  return r;
}

// ---- bf16 helpers ----
__device__ __forceinline__ float bflo(unsigned v){ return __uint_as_float(v << 16); }
__device__ __forceinline__ float bfhi(unsigned v){ return __uint_as_float(v & 0xFFFF0000u); }

// ---- index loader: handles int32 or int64 edge/batch arrays ----
__device__ __forceinline__ int ld_idx(const void* p, int i, int is64){
  if (is64) return (int)((const long long*)p)[i];
  return ((const int*)p)[i];
}

// wave-level dtype detect (1 => int64): int64 => every odd 32-bit word zero.
__device__ __forceinline__ int detect64(const unsigned* __restrict__ e_raw, int e){
  int lane = threadIdx.x & 63;
  int lim = (e < 1024) ? e : 1024;
  int nz = 0;
  for (int i = lane; i < lim; i += 64) nz |= (e_raw[2*i + 1] != 0u);
  return (__ballot(nz != 0) == 0ull) ? 1 : 0;
}

// ---- MFMA GEMM body: Yb[n,NC](bf16) = X[n,128] @ W[128,NC](f32)
// BIN=0: X is f32 (converted during staging); BIN=1: X already bf16.
template<int NC, int BIN>
__device__ __forceinline__ void gemm_body(const void* __restrict__ Xv,
                                          const float* __restrict__ W,
                                          unsigned short* __restrict__ Yb,
                                          int n, int blk, char* Alds){
  constexpr int NCF = NC/16;
  constexpr int WPC = 8/NCF;
  constexpr int RT  = 8/WPC;
  const int tid  = threadIdx.x;
  const int wave = tid >> 6, lane = tid & 63;
  const int rb = blk * 128;

  const int cbase = (wave % NCF) * 16;
  const int rt0   = (wave / NCF) * RT;
  const int col   = cbase + (lane & 15);
  const int kr0   = (lane >> 4) * 8;
  FU bu[4];
#pragma unroll
  for (int ks = 0; ks < 4; ++ks){
    float wv[8];
#pragma unroll
    for (int j = 0; j < 8; ++j) wv[j] = W[(size_t)(ks*32 + kr0 + j)*NC + col];
#pragma unroll
    for (int q = 0; q < 4; ++q) bu[ks].u[q] = cvtpk(wv[2*q], wv[2*q+1]);
  }

  // stage A tile (128 rows x 128 k) as bf16, byte ^= (row&7)<<4
  for (int i = tid; i < 128*32; i += 512){
    int row = i >> 5, kq = i & 31;            // kq: 8-byte unit along k
    int rsrc = rb + row; if (rsrc >= n) rsrc = n - 1;
    uint2 dw;
    if (BIN){
      dw = ((const uint2*)Xv)[(size_t)rsrc*32 + kq];      // 4 bf16 copy
    } else {
      f4 xv = ((const f4*)Xv)[(size_t)rsrc*32 + kq];
      dw = make_uint2(cvtpk(xv[0], xv[1]), cvtpk(xv[2], xv[3]));
    }
    int byte = (row*256 + kq*8) ^ ((row & 7) << 4);
    *reinterpret_cast<uint2*>(Alds + byte) = dw;
  }
  __syncthreads();

  f4 acc[RT];
#pragma unroll
  for (int rt = 0; rt < RT; ++rt) acc[rt] = 0.0f;

#pragma unroll
  for (int rt = 0; rt < RT; ++rt){
    const int arow = (rt0 + rt)*16 + (lane & 15);
#pragma unroll
    for (int ks = 0; ks < 4; ++ks){
      int kb = ks*32 + kr0;
      int byte = (arow*256 + kb*2) ^ ((arow & 7) << 4);
      s8 a = *reinterpret_cast<const s8*>(Alds + byte);
      acc[rt] = __builtin_amdgcn_mfma_f32_16x16x32_bf16(a, bu[ks].s, acc[rt], 0, 0, 0);
    }
  }

#pragma unroll
  for (int rt = 0; rt < RT; ++rt){
    int rowb = rb + (rt0 + rt)*16 + 4*(lane >> 4);
#pragma unroll
    for (int r = 0; r < 4; ++r){
      int row = rowb + r;
      if (row < n) Yb[(size_t)row*NC + col] = (unsigned short)cvtpk(acc[rt][r], acc[rt][r]);
    }
  }
}

template<int NC, int BIN>
__global__ __launch_bounds__(512) void gemm_k(const void* __restrict__ X,
                                              const float* __restrict__ W,
                                              unsigned short* __restrict__ Yb, int n){
  __shared__ int4 AldsV[2048];
  gemm_body<NC, BIN>(X, W, Yb, n, blockIdx.x, (char*)AldsV);
}

// ---- fused: gemm1 (blocks < GB) || bucket-count + edge compaction.
// etmp[i] = s | (d&127)<<16 | (d>>7)<<23  (needs s<65536, NBK<512)
// counts layout: counts[bin*CB + blk] (bin-major flat order)
__global__ __launch_bounds__(512) void fused1_k(const float* __restrict__ X,
                                                const float* __restrict__ W1,
                                                unsigned short* __restrict__ Yb,
                                                const void* __restrict__ eidx,
                                                const void* __restrict__ batchp,
                                                int* __restrict__ counts,
                                                unsigned* __restrict__ etmp,
                                                int* __restrict__ batch32,
                                                int n, int e, int GB, int CB){
  __shared__ int4 AldsV[2048];
  __shared__ int hist[512];
  int blk = blockIdx.x;
  if (blk < GB){
    gemm_body<128, 0>(X, W1, Yb, n, blk, (char*)AldsV);
    return;
  }
  blk -= GB;                          // 0..CB-1
  const int NBK = (n + 127) >> 7;
  for (int i = threadIdx.x; i < NBK; i += 512) hist[i] = 0;
  __syncthreads();
  int is64 = detect64((const unsigned*)eidx, e);
  int CHK = (e + CB - 1) / CB;
  int beg = blk*CHK, end = min(e, beg + CHK);
  for (int i = beg + (int)threadIdx.x; i < end; i += 512){
    int s = ld_idx(eidx, i, is64);
    int d = ld_idx(eidx, e + i, is64);
    atomicAdd(&hist[d >> 7], 1);      // LDS atomic
    etmp[i] = (unsigned)s | ((unsigned)(d & 127) << 16) | ((unsigned)(d >> 7) << 23);
  }
  __syncthreads();
  for (int i = threadIdx.x; i < NBK; i += 512) counts[i*CB + blk] = hist[i];
  for (int i = blk*512 + (int)threadIdx.x; i < n; i += CB*512)
    batch32[i] = ld_idx(batchp, i, is64);
}

// ---- flat scan level 1: block-local exclusive scan + block sums.
// CB == 256 == scan width so scan-block b == bucket b; block 0 zeroes outsum.
__global__ void scanA_k(const int* __restrict__ counts, int* __restrict__ base,
                        int* __restrict__ bsum, int L,
                        float* __restrict__ outsum, int totalOut){
  __shared__ int sh[256];
  int tid = threadIdx.x;
  int i = blockIdx.x*256 + tid;
  int v = (i < L) ? counts[i] : 0;
  sh[tid] = v; __syncthreads();
  for (int off = 1; off < 256; off <<= 1){
    int t = (tid >= off) ? sh[tid - off] : 0;
    __syncthreads();
    sh[tid] += t;
    __syncthreads();
  }
  if (i < L) base[i] = sh[tid] - v;
  if (tid == 255) bsum[blockIdx.x] = sh[255];
  if (blockIdx.x == 0){
    for (int k = tid; k < totalOut; k += 256) outsum[k] = 0.0f;
  }
}

// ---- scatter (with inline level-2 scan of bsum): edges -> bucket groups.
// Each block redundantly scans bsum[NBK] in LDS; block 0 publishes bsumS.
__global__ __launch_bounds__(512) void scat_k(const unsigned* __restrict__ etmp,
                                              const int* __restrict__ base,
                                              const int* __restrict__ bsum,
                                              int* __restrict__ bsumS,
                                              int* __restrict__ packed,
                                              int n, int e, int CB){
  __shared__ int sh[512];
  __shared__ int cur[512];
  int blk = blockIdx.x, tid = threadIdx.x;
  const int NBK = (n + 127) >> 7;
  int v = (tid < NBK) ? bsum[tid] : 0;
  sh[tid] = v; __syncthreads();
  for (int o = 1; o < 512; o <<= 1){
    int t = (tid >= o) ? sh[tid - o] : 0;
    __syncthreads();
    sh[tid] += t;
    __syncthreads();
  }
  int ex = sh[tid] - v;                     // exclusive bucket base
  if (tid < NBK) cur[tid] = ex + base[tid*CB + blk];
  if (blk == 0){
    if (tid < NBK) bsumS[tid] = ex;
    if (tid == NBK - 1) bsumS[NBK] = sh[tid];   // total = e
  }
  __syncthreads();
  int CHK = (e + CB - 1) / CB;
  int beg = blk*CHK, end = min(e, beg + CHK);
  for (int i = beg + tid; i < end; i += 512){
    unsigned w = etmp[i];
    int pos = atomicAdd(&cur[w >> 23], 1);
    packed[pos] = (int)(w & 0x7FFFFFu);     // s | dlow<<16
  }
}

// ---- per-bucket CSR build: 128-bin LDS counting sort, degrees, dinv ----
#define CSR_CAP 6144
__global__ __launch_bounds__(256) void csr_k(const int* __restrict__ packed,
                                             const int* __restrict__ bsumS,
                                             int* __restrict__ esrcS,
                                             int* __restrict__ rowptr,
                                             float* __restrict__ dinv, int n, int e){
  __shared__ int vals[CSR_CAP];
  __shared__ int hist[128], off[128], cur[128];
  int b = blockIdx.x, tid = threadIdx.x;
  if (b == 0 && tid == 0) rowptr[n] = e;
  int sbeg = bsumS[b], send = bsumS[b + 1];
  int m = send - sbeg;
  int mL = min(m, CSR_CAP);
  for (int i = tid; i < mL; i += 256) vals[i] = packed[sbeg + i];
  if (tid < 128) hist[tid] = 0;
  __syncthreads();
  for (int i = tid; i < m; i += 256){
    int v = (i < CSR_CAP) ? vals[i] : packed[sbeg + i];
    atomicAdd(&hist[(v >> 16) & 127], 1);
  }
  __syncthreads();
  if (tid < 128) off[tid] = hist[tid];
  __syncthreads();
  for (int o = 1; o < 128; o <<= 1){
    int v = 0;
    if (tid < 128 && tid >= o) v = off[tid - o];
    __syncthreads();
    if (tid < 128) off[tid] += v;
    __syncthreads();
  }
  if (tid < 128){
    int ex = off[tid] - hist[tid];      // exclusive
    cur[tid] = ex;
    int node = b*128 + tid;
    if (node < n){
      rowptr[node] = sbeg + ex;
      dinv[node] = rsqrtf((float)hist[tid] + 1.0f);
    }
  }
  __syncthreads();
  for (int i = tid; i < m; i += 256){
    int v = (i < CSR_CAP) ? vals[i] : packed[sbeg + i];
    int pos = atomicAdd(&cur[(v >> 16) & 127], 1);
    esrcS[sbeg + pos] = v & 0xFFFF;
  }
}

// ---- layer-1 aggregation + bias + relu -> bf16 h1. One wave per node,
// unroll-by-16 load-then-FMA (16 gathers in flight per wave).
__global__ __launch_bounds__(256) void agg128_k(const unsigned short* __restrict__ HWb,
                                                const float* __restrict__ dinv,
                                                const int* __restrict__ rowptr,
                                                const int* __restrict__ esrcS,
                                                const float* __restrict__ bias,
                                                unsigned* __restrict__ Hb, int n){
  int wid  = (blockIdx.x*256 + threadIdx.x) >> 6;
  int lane = threadIdx.x & 63;
  if (wid >= n) return;
  wid = __builtin_amdgcn_readfirstlane(wid);
  float di = dinv[wid];
  float di2 = di * di;
  int beg = __builtin_amdgcn_readfirstlane(rowptr[wid]);
  int end = __builtin_amdgcn_readfirstlane(rowptr[wid + 1]);
  unsigned sv = ((const unsigned*)(HWb + (size_t)wid*128))[lane];
  float a0 = bflo(sv) * di2, a1 = bfhi(sv) * di2;
  int j = beg;
  for (; j + 16 <= end; j += 16){
    int s[16]; float dv[16]; unsigned v[16];
#pragma unroll
    for (int t = 0; t < 16; ++t) s[t] = esrcS[j + t];
#pragma unroll
    for (int t = 0; t < 16; ++t){
      dv[t] = dinv[s[t]];
      v[t] = ((const unsigned*)(HWb + (size_t)s[t]*128))[lane];
    }
#pragma unroll
    for (int t = 0; t < 16; ++t){
      float wt = dv[t] * di;
      a0 += bflo(v[t]) * wt;
      a1 += bfhi(v[t]) * wt;
    }
  }
  for (; j + 4 <= end; j += 4){
    int s[4]; float dv[4]; unsigned v[4];
#pragma unroll
    for (int t = 0; t < 4; ++t) s[t] = esrcS[j + t];
#pragma unroll
    for (int t = 0; t < 4; ++t){
      dv[t] = dinv[s[t]];
      v[t] = ((const unsigned*)(HWb + (size_t)s[t]*128))[lane];
    }
#pragma unroll
    for (int t = 0; t < 4; ++t){
      float wt = dv[t] * di;
      a0 += bflo(v[t]) * wt;
      a1 += bfhi(v[t]) * wt;
    }
  }
  for (; j < end; ++j){
    int s = esrcS[j];
    float wt = dinv[s] * di;
    unsigned v = ((const unsigned*)(HWb + (size_t)s*128))[lane];
    a0 += bflo(v) * wt;
    a1 += bfhi(v) * wt;
  }
  f2 bb = ((const f2*)bias)[lane];
  a0 = fmaxf(a0 + bb[0], 0.0f);
  a1 = fmaxf(a1 + bb[1], 0.0f);
  Hb[(size_t)wid*64 + lane] = cvtpk(a0, a1);
}

// ---- layer-2 aggregation + bias + relu -> f32 h2 (for pool) ----
__global__ __launch_bounds__(256) void agg64_k(const unsigned short* __restrict__ HWb,
                                               const float* __restrict__ dinv,
                                               const int* __restrict__ rowptr,
                                               const int* __restrict__ esrcS,
                                               const float* __restrict__ bias,
                                               float* __restrict__ H2, int n){
  int wid  = (blockIdx.x*256 + threadIdx.x) >> 6;
  int lane = threadIdx.x & 63;
  if (wid >= n) return;
  wid = __builtin_amdgcn_readfirstlane(wid);
  float di = dinv[wid];
  float di2 = di * di;
  int beg = __builtin_amdgcn_readfirstlane(rowptr[wid]);
  int end = __builtin_amdgcn_readfirstlane(rowptr[wid + 1]);
  float acc = bflo((unsigned)HWb[(size_t)wid*64 + lane]) * di2;
  int j = beg;
  for (; j + 16 <= end; j += 16){
    int s[16]; float dv[16]; unsigned v[16];
#pragma unroll
    for (int t = 0; t < 16; ++t) s[t] = esrcS[j + t];
#pragma unroll
    for (int t = 0; t < 16; ++t){
      dv[t] = dinv[s[t]];
      v[t] = (unsigned)HWb[(size_t)s[t]*64 + lane];
    }
#pragma unroll
    for (int t = 0; t < 16; ++t) acc += bflo(v[t]) * (dv[t] * di);
  }
  for (; j + 4 <= end; j += 4){
    int s[4]; float dv[4]; unsigned v[4];
#pragma unroll
    for (int t = 0; t < 4; ++t) s[t] = esrcS[j + t];
#pragma unroll
    for (int t = 0; t < 4; ++t){
      dv[t] = dinv[s[t]];
      v[t] = (unsigned)HWb[(size_t)s[t]*64 + lane];
    }
#pragma unroll
    for (int t = 0; t < 4; ++t) acc += bflo(v[t]) * (dv[t] * di);
  }
  for (; j < end; ++j){
    int s = esrcS[j];
    acc += bflo((unsigned)HWb[(size_t)s*64 + lane]) * (dinv[s] * di);
  }
  acc = fmaxf(acc + bias[lane], 0.0f);
  H2[(size_t)wid*64 + lane] = acc;
}

// ---- mean pool: 8 nodes per wave, unrolled loads, run-length atomics ----
__global__ __launch_bounds__(256) void pool_k(const float* __restrict__ H2,
                                              const int* __restrict__ batch32,
                                              float* __restrict__ outsum, int n){
  int wid  = (blockIdx.x*256 + threadIdx.x) >> 6;
  int lane = threadIdx.x & 63;
  int start = wid * 8;
  if (start >= n) return;
  int cnt = min(8, n - start);
  float v[8]; int b[8];
#pragma unroll
  for (int t = 0; t < 8; ++t){
    int i = start + t; if (i >= n) i = n - 1;
    v[t] = H2[(size_t)i*64 + lane];
    b[t] = batch32[i];
  }
  float acc = 0.0f;
  int gcur = b[0];
#pragma unroll
  for (int t = 0; t < 8; ++t){
    if (t < cnt){
      if (b[t] != gcur){
        unsafeAtomicAdd(&outsum[gcur*64 + lane], acc);
        acc = 0.0f; gcur = b[t];
      }
      acc += v[t];
    }
  }
  unsafeAtomicAdd(&outsum[gcur*64 + lane], acc);
}

// ---- finalize: graph sizes via binary search on sorted batch + divide ----
__global__ void fin_k(const float* __restrict__ outsum,
                      const int* __restrict__ batch32,
                      float* __restrict__ out, int n, int g){
  __shared__ int starts[257];
  int t = threadIdx.x;
  if (t <= g){
    int lo = 0, hi = n;
    while (lo < hi){ int mid = (lo + hi) >> 1; if (batch32[mid] < t) lo = mid + 1; else hi = mid; }
    starts[t] = lo;
  }
  __syncthreads();
  for (int idx = t; idx < (g << 6); idx += 256){
    int gi = idx >> 6;
    float c = (float)(starts[gi + 1] - starts[gi]);
    out[idx] = outsum[idx] / fmaxf(c, 1.0f);
  }
}

extern "C" void kernel_launch(void* const* d_in, const int* in_sizes, int n_in,
                              void* d_out, int out_size, void* d_ws, size_t ws_size,
                              hipStream_t stream){
  const float* x    = (const float*)d_in[0];
  const float* W1   = (const float*)d_in[1];
  const float* b1   = (const float*)d_in[2];
  const float* W2   = (const float*)d_in[3];
  const float* b2   = (const float*)d_in[4];
  const void*  eidx = d_in[5];
  const void*  batchp = d_in[6];
  const int n = in_sizes[0] / 128;    // 50000
  const int e = in_sizes[5] / 2;      // 800000
  const int g = out_size / 64;        // 64 graphs
  float* out = (float*)d_out;

  const int NBK = (n + 127) >> 7;     // dst buckets (n <= 65536 required)
  const int CB  = 256;                // count/scatter blocks (== scan width)
  const int GB  = (n + 127) / 128;    // gemm M-tiles
  const int L   = NBK * CB;           // flat counts length

  // ---- workspace layout ----
  char* w = (char*)d_ws;
  int* counts  = (int*)w;                     // L (bin-major)
  int* base    = counts + (size_t)L;          // L
  int* bsum    = base + (size_t)L;            // NBK
  int* bsumS   = bsum + NBK;                  // NBK+1 (scanned copy)
  int* rowptr  = bsumS + (NBK + 1);           // n+1
  int* batch32 = rowptr + (n + 1);            // n
  float* dinv  = (float*)(batch32 + n);       // n
  float* outsum = dinv + n;                   // out_size
  unsigned* etmp = (unsigned*)(outsum + out_size);   // e
  int* packed  = (int*)(etmp + e);            // e
  int* esrcS   = packed + e;                  // e
  size_t ofs = (size_t)((char*)(esrcS + e) - w);
  ofs = (ofs + 255) & ~(size_t)255;
  unsigned short* HWb = (unsigned short*)(w + ofs);   // n*128 bf16 (gemm out)
  size_t ofs2 = ofs + (size_t)n * 128 * 2;
  ofs2 = (ofs2 + 255) & ~(size_t)255;
  unsigned short* Hb = (unsigned short*)(w + ofs2);   // n*128 bf16 (h1)
  size_t ofs3 = ofs2 + (size_t)n * 128 * 2;
  ofs3 = (ofs3 + 255) & ~(size_t)255;
  float* H2 = (float*)(w + ofs3);             // n*64 f32 (h2)

  fused1_k<<<GB + CB, 512, 0, stream>>>(x, W1, HWb, eidx, batchp,
                                        counts, etmp, batch32, n, e, GB, CB);
  scanA_k<<<NBK, 256, 0, stream>>>(counts, base, bsum, L, outsum, out_size);
  scat_k<<<CB, 512, 0, stream>>>(etmp, base, bsum, bsumS, packed, n, e, CB);
  csr_k<<<NBK, 256, 0, stream>>>(packed, bsumS, esrcS, rowptr, dinv, n, e);

  agg128_k<<<(n + 3)/4, 256, 0, stream>>>(HWb, dinv, rowptr, esrcS, b1,
                                          (unsigned*)Hb, n);
  gemm_k<64, 1><<<GB, 512, 0, stream>>>(Hb, W2, HWb, n);
  agg64_k<<<(n + 3)/4, 256, 0, stream>>>(HWb, dinv, rowptr, esrcS, b2, H2, n);

  int pw = (n + 7)/8;
  pool_k<<<(pw + 3)/4, 256, 0, stream>>>(H2, batch32, outsum, n);
  fin_k<<<1, 256, 0, stream>>>(outsum, batch32, out, n, g);
}

// Round 13
// 115.856 us; speedup vs baseline: 1.3964x; 1.0373x over previous
//
#include <hip/hip_runtime.h>

typedef float f4 __attribute__((ext_vector_type(4)));
typedef float f2 __attribute__((ext_vector_type(2)));
typedef short s8 __attribute__((ext_vector_type(8)));

union FU { unsigned u[4]; s8 s; };

// packed f32x2 -> bf16x2 (RNE) in one instruction
__device__ __forceinline__ unsigned cvtpk(float lo, float hi){
  unsigned r;
  asm("v_cvt_pk_bf16_f32 %0, %1, %2" : "=v"(r) : "v"(lo), "v"(hi));
  return r;
}

// ---- bf16 helpers ----
__device__ __forceinline__ float bflo(unsigned v){ return __uint_as_float(v << 16); }
__device__ __forceinline__ float bfhi(unsigned v){ return __uint_as_float(v & 0xFFFF0000u); }

// ---- index loader: handles int32 or int64 edge/batch arrays ----
__device__ __forceinline__ int ld_idx(const void* p, int i, int is64){
  if (is64) return (int)((const long long*)p)[i];
  return ((const int*)p)[i];
}

// wave-level dtype detect (1 => int64): int64 => every odd 32-bit word zero.
__device__ __forceinline__ int detect64(const unsigned* __restrict__ e_raw, int e){
  int lane = threadIdx.x & 63;
  int lim = (e < 1024) ? e : 1024;
  int nz = 0;
  for (int i = lane; i < lim; i += 64) nz |= (e_raw[2*i + 1] != 0u);
  return (__ballot(nz != 0) == 0ull) ? 1 : 0;
}

// ---- MFMA GEMM body: Yb[n,NC](bf16) = X[n,128] @ W[128,NC](f32)
// BIN=0: X is f32 (converted during staging); BIN=1: X already bf16.
template<int NC, int BIN>
__device__ __forceinline__ void gemm_body(const void* __restrict__ Xv,
                                          const float* __restrict__ W,
                                          unsigned short* __restrict__ Yb,
                                          int n, int blk, char* Alds){
  constexpr int NCF = NC/16;
  constexpr int WPC = 8/NCF;
  constexpr int RT  = 8/WPC;
  const int tid  = threadIdx.x;
  const int wave = tid >> 6, lane = tid & 63;
  const int rb = blk * 128;

  const int cbase = (wave % NCF) * 16;
  const int rt0   = (wave / NCF) * RT;
  const int col   = cbase + (lane & 15);
  const int kr0   = (lane >> 4) * 8;
  FU bu[4];
#pragma unroll
  for (int ks = 0; ks < 4; ++ks){
    float wv[8];
#pragma unroll
    for (int j = 0; j < 8; ++j) wv[j] = W[(size_t)(ks*32 + kr0 + j)*NC + col];
#pragma unroll
    for (int q = 0; q < 4; ++q) bu[ks].u[q] = cvtpk(wv[2*q], wv[2*q+1]);
  }

  // stage A tile (128 rows x 128 k) as bf16, byte ^= (row&7)<<4
  for (int i = tid; i < 128*32; i += 512){
    int row = i >> 5, kq = i & 31;            // kq: 8-byte unit along k
    int rsrc = rb + row; if (rsrc >= n) rsrc = n - 1;
    uint2 dw;
    if (BIN){
      dw = ((const uint2*)Xv)[(size_t)rsrc*32 + kq];      // 4 bf16 copy
    } else {
      f4 xv = ((const f4*)Xv)[(size_t)rsrc*32 + kq];
      dw = make_uint2(cvtpk(xv[0], xv[1]), cvtpk(xv[2], xv[3]));
    }
    int byte = (row*256 + kq*8) ^ ((row & 7) << 4);
    *reinterpret_cast<uint2*>(Alds + byte) = dw;
  }
  __syncthreads();

  f4 acc[RT];
#pragma unroll
  for (int rt = 0; rt < RT; ++rt) acc[rt] = 0.0f;

#pragma unroll
  for (int rt = 0; rt < RT; ++rt){
    const int arow = (rt0 + rt)*16 + (lane & 15);
#pragma unroll
    for (int ks = 0; ks < 4; ++ks){
      int kb = ks*32 + kr0;
      int byte = (arow*256 + kb*2) ^ ((arow & 7) << 4);
      s8 a = *reinterpret_cast<const s8*>(Alds + byte);
      acc[rt] = __builtin_amdgcn_mfma_f32_16x16x32_bf16(a, bu[ks].s, acc[rt], 0, 0, 0);
    }
  }

#pragma unroll
  for (int rt = 0; rt < RT; ++rt){
    int rowb = rb + (rt0 + rt)*16 + 4*(lane >> 4);
#pragma unroll
    for (int r = 0; r < 4; ++r){
      int row = rowb + r;
      if (row < n) Yb[(size_t)row*NC + col] = (unsigned short)cvtpk(acc[rt][r], acc[rt][r]);
    }
  }
}

template<int NC, int BIN>
__global__ __launch_bounds__(512) void gemm_k(const void* __restrict__ X,
                                              const float* __restrict__ W,
                                              unsigned short* __restrict__ Yb, int n){
  __shared__ int4 AldsV[2048];
  gemm_body<NC, BIN>(X, W, Yb, n, blockIdx.x, (char*)AldsV);
}

// ---- fused: gemm1 (blocks < GB) || bucket-count + edge compaction.
// etmp[i] = s | (d&127)<<16 | (d>>7)<<23  (needs s<65536, NBK<512)
__global__ __launch_bounds__(512) void fused1_k(const float* __restrict__ X,
                                                const float* __restrict__ W1,
                                                unsigned short* __restrict__ Yb,
                                                const void* __restrict__ eidx,
                                                const void* __restrict__ batchp,
                                                int* __restrict__ counts,
                                                unsigned* __restrict__ etmp,
                                                int* __restrict__ batch32,
                                                int n, int e, int GB, int CB){
  __shared__ int4 AldsV[2048];
  __shared__ int hist[512];
  int blk = blockIdx.x;
  if (blk < GB){
    gemm_body<128, 0>(X, W1, Yb, n, blk, (char*)AldsV);
    return;
  }
  blk -= GB;                          // 0..CB-1
  const int NBK = (n + 127) >> 7;
  for (int i = threadIdx.x; i < NBK; i += 512) hist[i] = 0;
  __syncthreads();
  int is64 = detect64((const unsigned*)eidx, e);
  int CHK = (e + CB - 1) / CB;
  int beg = blk*CHK, end = min(e, beg + CHK);
  for (int i = beg + (int)threadIdx.x; i < end; i += 512){
    int s = ld_idx(eidx, i, is64);
    int d = ld_idx(eidx, e + i, is64);
    atomicAdd(&hist[d >> 7], 1);      // LDS atomic
    etmp[i] = (unsigned)s | ((unsigned)(d & 127) << 16) | ((unsigned)(d >> 7) << 23);
  }
  __syncthreads();
  for (int i = threadIdx.x; i < NBK; i += 512) counts[i*CB + blk] = hist[i];
  for (int i = blk*512 + (int)threadIdx.x; i < n; i += CB*512)
    batch32[i] = ld_idx(batchp, i, is64);
}

// ---- flat scan level 1 + misc init (block 0: zero d_out, graph inv-counts)
__global__ void scanA_k(const int* __restrict__ counts, int* __restrict__ base,
                        int* __restrict__ bsum, int L,
                        const int* __restrict__ batch32, float* __restrict__ invc,
                        float* __restrict__ out, int n, int g){
  __shared__ int sh[256];
  __shared__ int starts[257];
  int tid = threadIdx.x;
  int i = blockIdx.x*256 + tid;
  int v = (i < L) ? counts[i] : 0;
  sh[tid] = v; __syncthreads();
  for (int off = 1; off < 256; off <<= 1){
    int t = (tid >= off) ? sh[tid - off] : 0;
    __syncthreads();
    sh[tid] += t;
    __syncthreads();
  }
  if (i < L) base[i] = sh[tid] - v;
  if (tid == 255) bsum[blockIdx.x] = sh[255];
  if (blockIdx.x == 0){
    if (tid <= g){
      int lo = 0, hi = n;
      while (lo < hi){ int mid = (lo + hi) >> 1; if (batch32[mid] < tid) lo = mid + 1; else hi = mid; }
      starts[tid] = lo;
    }
    __syncthreads();
    if (tid < g){
      float c = (float)(starts[tid + 1] - starts[tid]);
      invc[tid] = 1.0f / fmaxf(c, 1.0f);
    }
    for (int k = tid; k < (g << 6); k += 256) out[k] = 0.0f;
  }
}

// ---- scatter (with inline level-2 scan of bsum): edges -> bucket groups.
__global__ __launch_bounds__(512) void scat_k(const unsigned* __restrict__ etmp,
                                              const int* __restrict__ base,
                                              const int* __restrict__ bsum,
                                              int* __restrict__ bsumS,
                                              int* __restrict__ packed,
                                              int n, int e, int CB){
  __shared__ int sh[512];
  __shared__ int cur[512];
  int blk = blockIdx.x, tid = threadIdx.x;
  const int NBK = (n + 127) >> 7;
  int v = (tid < NBK) ? bsum[tid] : 0;
  sh[tid] = v; __syncthreads();
  for (int o = 1; o < 512; o <<= 1){
    int t = (tid >= o) ? sh[tid - o] : 0;
    __syncthreads();
    sh[tid] += t;
    __syncthreads();
  }
  int ex = sh[tid] - v;                     // exclusive bucket base
  if (tid < NBK) cur[tid] = ex + base[tid*CB + blk];
  if (blk == 0){
    if (tid < NBK) bsumS[tid] = ex;
    if (tid == NBK - 1) bsumS[NBK] = sh[tid];   // total = e
  }
  __syncthreads();
  int CHK = (e + CB - 1) / CB;
  int beg = blk*CHK, end = min(e, beg + CHK);
  for (int i = beg + tid; i < end; i += 512){
    unsigned w = etmp[i];
    int pos = atomicAdd(&cur[w >> 23], 1);
    packed[pos] = (int)(w & 0x7FFFFFu);     // s | dlow<<16
  }
}

// ---- per-bucket CSR build: 128-bin LDS counting sort, degrees, dinv ----
#define CSR_CAP 6144
__global__ __launch_bounds__(256) void csr_k(const int* __restrict__ packed,
                                             const int* __restrict__ bsumS,
                                             int* __restrict__ esrcS,
                                             int* __restrict__ rowptr,
                                             float* __restrict__ dinv, int n, int e){
  __shared__ int vals[CSR_CAP];
  __shared__ int hist[128], off[128], cur[128];
  int b = blockIdx.x, tid = threadIdx.x;
  if (b == 0 && tid == 0) rowptr[n] = e;
  int sbeg = bsumS[b], send = bsumS[b + 1];
  int m = send - sbeg;
  int mL = min(m, CSR_CAP);
  for (int i = tid; i < mL; i += 256) vals[i] = packed[sbeg + i];
  if (tid < 128) hist[tid] = 0;
  __syncthreads();
  for (int i = tid; i < m; i += 256){
    int v = (i < CSR_CAP) ? vals[i] : packed[sbeg + i];
    atomicAdd(&hist[(v >> 16) & 127], 1);
  }
  __syncthreads();
  if (tid < 128) off[tid] = hist[tid];
  __syncthreads();
  for (int o = 1; o < 128; o <<= 1){
    int v = 0;
    if (tid < 128 && tid >= o) v = off[tid - o];
    __syncthreads();
    if (tid < 128) off[tid] += v;
    __syncthreads();
  }
  if (tid < 128){
    int ex = off[tid] - hist[tid];      // exclusive
    cur[tid] = ex;
    int node = b*128 + tid;
    if (node < n){
      rowptr[node] = sbeg + ex;
      dinv[node] = rsqrtf((float)hist[tid] + 1.0f);
    }
  }
  __syncthreads();
  for (int i = tid; i < m; i += 256){
    int v = (i < CSR_CAP) ? vals[i] : packed[sbeg + i];
    int pos = atomicAdd(&cur[(v >> 16) & 127], 1);
    esrcS[sbeg + pos] = v & 0xFFFF;
  }
}

// ---- layer-1 aggregation, quad-row gathers: lane (slot=lane>>4, cg=lane&15)
// loads 16B of row s[slot] -> one instr fetches 4 rows (1KB). Cross-slot
// reduce via shfl_xor(16/32). Output bf16 h1.
__global__ __launch_bounds__(256) void agg128_k(const unsigned short* __restrict__ HWb,
                                                const float* __restrict__ dinv,
                                                const int* __restrict__ rowptr,
                                                const int* __restrict__ esrcS,
                                                const float* __restrict__ bias,
                                                unsigned short* __restrict__ Hb, int n){
  int wid  = (blockIdx.x*256 + threadIdx.x) >> 6;
  int lane = threadIdx.x & 63;
  if (wid >= n) return;
  wid = __builtin_amdgcn_readfirstlane(wid);
  const int slot = lane >> 4;          // 0..3
  const int cg   = lane & 15;         // col group: cols cg*8 .. cg*8+7
  float di = dinv[wid];
  float di2 = di * di;
  int beg = __builtin_amdgcn_readfirstlane(rowptr[wid]);
  int end = __builtin_amdgcn_readfirstlane(rowptr[wid + 1]);
  float acc[8];
#pragma unroll
  for (int k = 0; k < 8; ++k) acc[k] = 0.0f;
  const char* Hc = (const char*)HWb;
  int j = beg;
  for (; j + 16 <= end; j += 16){
    int s[4]; float wt[4]; uint4 v[4];
#pragma unroll
    for (int q = 0; q < 4; ++q) s[q] = esrcS[j + q*4 + slot];
#pragma unroll
    for (int q = 0; q < 4; ++q){
      wt[q] = dinv[s[q]] * di;
      v[q] = *(const uint4*)(Hc + (size_t)s[q]*256 + cg*16);
    }
#pragma unroll
    for (int q = 0; q < 4; ++q){
      acc[0] += bflo(v[q].x)*wt[q]; acc[1] += bfhi(v[q].x)*wt[q];
      acc[2] += bflo(v[q].y)*wt[q]; acc[3] += bfhi(v[q].y)*wt[q];
      acc[4] += bflo(v[q].z)*wt[q]; acc[5] += bfhi(v[q].z)*wt[q];
      acc[6] += bflo(v[q].w)*wt[q]; acc[7] += bfhi(v[q].w)*wt[q];
    }
  }
  for (; j < end; j += 4){
    int idx = j + slot;
    int live = (idx < end);
    if (!live) idx = end - 1;         // dup row of last live edge: lines coalesce
    int s = esrcS[idx];
    float wt = live ? (dinv[s] * di) : 0.0f;
    uint4 v = *(const uint4*)(Hc + (size_t)s*256 + cg*16);
    acc[0] += bflo(v.x)*wt; acc[1] += bfhi(v.x)*wt;
    acc[2] += bflo(v.y)*wt; acc[3] += bfhi(v.y)*wt;
    acc[4] += bflo(v.z)*wt; acc[5] += bfhi(v.z)*wt;
    acc[6] += bflo(v.w)*wt; acc[7] += bfhi(v.w)*wt;
  }
  // reduce across the 4 slots (lane bits 4,5)
#pragma unroll
  for (int k = 0; k < 8; ++k){
    acc[k] += __shfl_xor(acc[k], 16);
    acc[k] += __shfl_xor(acc[k], 32);
  }
  // self-loop + bias + relu (each lane owns its col group)
  uint4 sv = *(const uint4*)(Hc + (size_t)wid*256 + cg*16);
  acc[0] += bflo(sv.x)*di2; acc[1] += bfhi(sv.x)*di2;
  acc[2] += bflo(sv.y)*di2; acc[3] += bfhi(sv.y)*di2;
  acc[4] += bflo(sv.z)*di2; acc[5] += bfhi(sv.z)*di2;
  acc[6] += bflo(sv.w)*di2; acc[7] += bfhi(sv.w)*di2;
  f4 b0 = *(const f4*)(bias + cg*8);
  f4 b1 = *(const f4*)(bias + cg*8 + 4);
#pragma unroll
  for (int k = 0; k < 4; ++k) acc[k] = fmaxf(acc[k] + b0[k], 0.0f);
#pragma unroll
  for (int k = 0; k < 4; ++k) acc[4+k] = fmaxf(acc[4+k] + b1[k], 0.0f);
  if (slot == 0){
    uint4 o;
    o.x = cvtpk(acc[0], acc[1]); o.y = cvtpk(acc[2], acc[3]);
    o.z = cvtpk(acc[4], acc[5]); o.w = cvtpk(acc[6], acc[7]);
    *(uint4*)((char*)Hb + (size_t)wid*256 + cg*16) = o;
  }
}

// ---- layer-2 aggregation, 8-row gathers (slot=lane>>3, cg=lane&7) -> f32 h2.
__global__ __launch_bounds__(256) void agg64_k(const unsigned short* __restrict__ HWb,
                                               const float* __restrict__ dinv,
                                               const int* __restrict__ rowptr,
                                               const int* __restrict__ esrcS,
                                               const float* __restrict__ bias,
                                               float* __restrict__ H2, int n){
  int wid  = (blockIdx.x*256 + threadIdx.x) >> 6;
  int lane = threadIdx.x & 63;
  if (wid >= n) return;
  wid = __builtin_amdgcn_readfirstlane(wid);
  const int slot = lane >> 3;          // 0..7
  const int cg   = lane & 7;           // cols cg*8 .. cg*8+7
  float di = dinv[wid];
  float di2 = di * di;
  int beg = __builtin_amdgcn_readfirstlane(rowptr[wid]);
  int end = __builtin_amdgcn_readfirstlane(rowptr[wid + 1]);
  float acc[8];
#pragma unroll
  for (int k = 0; k < 8; ++k) acc[k] = 0.0f;
  const char* Hc = (const char*)HWb;
  int j = beg;
  for (; j + 16 <= end; j += 16){
    int s[2]; float wt[2]; uint4 v[2];
#pragma unroll
    for (int q = 0; q < 2; ++q) s[q] = esrcS[j + q*8 + slot];
#pragma unroll
    for (int q = 0; q < 2; ++q){
      wt[q] = dinv[s[q]] * di;
      v[q] = *(const uint4*)(Hc + (size_t)s[q]*128 + cg*16);
    }
#pragma unroll
    for (int q = 0; q < 2; ++q){
      acc[0] += bflo(v[q].x)*wt[q]; acc[1] += bfhi(v[q].x)*wt[q];
      acc[2] += bflo(v[q].y)*wt[q]; acc[3] += bfhi(v[q].y)*wt[q];
      acc[4] += bflo(v[q].z)*wt[q]; acc[5] += bfhi(v[q].z)*wt[q];
      acc[6] += bflo(v[q].w)*wt[q]; acc[7] += bfhi(v[q].w)*wt[q];
    }
  }
  for (; j < end; j += 8){
    int idx = j + slot;
    int live = (idx < end);
    if (!live) idx = end - 1;
    int s = esrcS[idx];
    float wt = live ? (dinv[s] * di) : 0.0f;
    uint4 v = *(const uint4*)(Hc + (size_t)s*128 + cg*16);
    acc[0] += bflo(v.x)*wt; acc[1] += bfhi(v.x)*wt;
    acc[2] += bflo(v.y)*wt; acc[3] += bfhi(v.y)*wt;
    acc[4] += bflo(v.z)*wt; acc[5] += bfhi(v.z)*wt;
    acc[6] += bflo(v.w)*wt; acc[7] += bfhi(v.w)*wt;
  }
  // reduce across the 8 slots (lane bits 3,4,5)
#pragma unroll
  for (int k = 0; k < 8; ++k){
    acc[k] += __shfl_xor(acc[k], 8);
    acc[k] += __shfl_xor(acc[k], 16);
    acc[k] += __shfl_xor(acc[k], 32);
  }
  uint4 sv = *(const uint4*)(Hc + (size_t)wid*128 + cg*16);
  acc[0] += bflo(sv.x)*di2; acc[1] += bfhi(sv.x)*di2;
  acc[2] += bflo(sv.y)*di2; acc[3] += bfhi(sv.y)*di2;
  acc[4] += bflo(sv.z)*di2; acc[5] += bfhi(sv.z)*di2;
  acc[6] += bflo(sv.w)*di2; acc[7] += bfhi(sv.w)*di2;
  f4 b0 = *(const f4*)(bias + cg*8);
  f4 b1 = *(const f4*)(bias + cg*8 + 4);
#pragma unroll
  for (int k = 0; k < 4; ++k) acc[k] = fmaxf(acc[k] + b0[k], 0.0f);
#pragma unroll
  for (int k = 0; k < 4; ++k) acc[4+k] = fmaxf(acc[4+k] + b1[k], 0.0f);
  if (slot == 0){
    f4 o0; o0[0]=acc[0]; o0[1]=acc[1]; o0[2]=acc[2]; o0[3]=acc[3];
    f4 o1; o1[0]=acc[4]; o1[1]=acc[5]; o1[2]=acc[6]; o1[3]=acc[7];
    *(f4*)(H2 + (size_t)wid*64 + cg*8)     = o0;
    *(f4*)(H2 + (size_t)wid*64 + cg*8 + 4) = o1;
  }
}

// ---- mean pool: 8 nodes/wave, run-length atomics of acc*invc direct to out ----
__global__ __launch_bounds__(256) void pool_k(const float* __restrict__ H2,
                                              const int* __restrict__ batch32,
                                              const float* __restrict__ invc,
                                              float* __restrict__ out, int n){
  int wid  = (blockIdx.x*256 + threadIdx.x) >> 6;
  int lane = threadIdx.x & 63;
  int start = wid * 8;
  if (start >= n) return;
  int cnt = min(8, n - start);
  float v[8]; int b[8];
#pragma unroll
  for (int t = 0; t < 8; ++t){
    int i = start + t; if (i >= n) i = n - 1;
    v[t] = H2[(size_t)i*64 + lane];
    b[t] = batch32[i];
  }
  float acc = 0.0f;
  int gcur = b[0];
#pragma unroll
  for (int t = 0; t < 8; ++t){
    if (t < cnt){
      if (b[t] != gcur){
        unsafeAtomicAdd(&out[gcur*64 + lane], acc * invc[gcur]);
        acc = 0.0f; gcur = b[t];
      }
      acc += v[t];
    }
  }
  unsafeAtomicAdd(&out[gcur*64 + lane], acc * invc[gcur]);
}

extern "C" void kernel_launch(void* const* d_in, const int* in_sizes, int n_in,
                              void* d_out, int out_size, void* d_ws, size_t ws_size,
                              hipStream_t stream){
  const float* x    = (const float*)d_in[0];
  const float* W1   = (const float*)d_in[1];
  const float* b1   = (const float*)d_in[2];
  const float* W2   = (const float*)d_in[3];
  const float* b2   = (const float*)d_in[4];
  const void*  eidx = d_in[5];
  const void*  batchp = d_in[6];
  const int n = in_sizes[0] / 128;    // 50000
  const int e = in_sizes[5] / 2;      // 800000
  const int g = out_size / 64;        // 64 graphs
  float* out = (float*)d_out;

  const int NBK = (n + 127) >> 7;     // dst buckets (n <= 65536 required)
  const int CB  = 256;                // count/scatter blocks (== scan width)
  const int GB  = (n + 127) / 128;    // gemm M-tiles
  const int L   = NBK * CB;           // flat counts length

  // ---- workspace layout ----
  char* w = (char*)d_ws;
  int* counts  = (int*)w;                     // L (bin-major)
  int* base    = counts + (size_t)L;          // L
  int* bsum    = base + (size_t)L;            // NBK
  int* bsumS   = bsum + NBK;                  // NBK+1 (scanned copy)
  int* rowptr  = bsumS + (NBK + 1);           // n+1
  int* batch32 = rowptr + (n + 1);            // n
  float* dinv  = (float*)(batch32 + n);       // n
  float* invc  = dinv + n;                    // g
  unsigned* etmp = (unsigned*)(invc + g);     // e
  int* packed  = (int*)(etmp + e);            // e
  int* esrcS   = packed + e;                  // e
  size_t ofs = (size_t)((char*)(esrcS + e) - w);
  ofs = (ofs + 255) & ~(size_t)255;
  unsigned short* HWb = (unsigned short*)(w + ofs);   // n*128 bf16 (gemm out)
  size_t ofs2 = ofs + (size_t)n * 128 * 2;
  ofs2 = (ofs2 + 255) & ~(size_t)255;
  unsigned short* Hb = (unsigned short*)(w + ofs2);   // n*128 bf16 (h1)
  size_t ofs3 = ofs2 + (size_t)n * 128 * 2;
  ofs3 = (ofs3 + 255) & ~(size_t)255;
  float* H2 = (float*)(w + ofs3);             // n*64 f32 (h2)

  fused1_k<<<GB + CB, 512, 0, stream>>>(x, W1, HWb, eidx, batchp,
                                        counts, etmp, batch32, n, e, GB, CB);
  scanA_k<<<NBK, 256, 0, stream>>>(counts, base, bsum, L, batch32, invc, out, n, g);
  scat_k<<<CB, 512, 0, stream>>>(etmp, base, bsum, bsumS, packed, n, e, CB);
  csr_k<<<NBK, 256, 0, stream>>>(packed, bsumS, esrcS, rowptr, dinv, n, e);

  agg128_k<<<(n + 3)/4, 256, 0, stream>>>(HWb, dinv, rowptr, esrcS, b1, Hb, n);
  gemm_k<64, 1><<<GB, 512, 0, stream>>>(Hb, W2, HWb, n);
  agg64_k<<<(n + 3)/4, 256, 0, stream>>>(HWb, dinv, rowptr, esrcS, b2, H2, n);

  int pw = (n + 7)/8;
  pool_k<<<(pw + 3)/4, 256, 0, stream>>>(H2, batch32, invc, out, n);
}